// Round 7
// baseline (271.598 us; speedup 1.0000x reference)
//
#include <hip/hip_runtime.h>
#include <stdint.h>
#include <stddef.h>

#define BDIM 4
#define QUE  128
#define VAL  128
#define DD   512
#define BQ   (BDIM*QUE)
#define BK   32

typedef float    f32x4 __attribute__((ext_vector_type(4)));
typedef float    f32x2 __attribute__((ext_vector_type(2)));
typedef _Float16 f16x8 __attribute__((ext_vector_type(8)));
typedef _Float16 f16x4 __attribute__((ext_vector_type(4)));
typedef _Float16 f16x2 __attribute__((ext_vector_type(2)));

// ---------------- prep: fp16 transposes  W1->W1T[e][d], Wse->WseT[d][e],
//                  vs->vsT[b][d][v] -------------------------------------------
__global__ __launch_bounds__(256) void prep_kernel(const float* __restrict__ W1,
                                                   _Float16* __restrict__ W1T,
                                                   const float* __restrict__ Wse,
                                                   _Float16* __restrict__ WseT,
                                                   const float* __restrict__ vs,
                                                   _Float16* __restrict__ vsT) {
    __shared__ float tile[32][33];
    const int tx = threadIdx.x & 31;
    const int ty = threadIdx.x >> 5;      // 0..7
    const int gx = blockIdx.x, gy = blockIdx.y;
    if (gy < 32) {
        const float* src = (gy < 16) ? W1  : Wse;
        _Float16*    dst = (gy < 16) ? W1T : WseT;
        int a0 = gx * 32;                 // source-row tile
        int b0 = (gy & 15) * 32;          // source-col tile
        #pragma unroll
        for (int r = 0; r < 4; ++r)
            tile[ty + r*8][tx] = src[(size_t)(a0 + ty + r*8) * DD + b0 + tx];
        __syncthreads();
        #pragma unroll
        for (int r = 0; r < 4; ++r) {
            int el = ty + r*8;
            dst[(size_t)(b0 + el) * DD + a0 + tx] = (_Float16)tile[tx][el];
        }
    } else {
        // vs[b][v][d] -> vsT[b][d][v], b = gy-32, d-tile = gx
        int bb = gy - 32;
        const float* src = vs  + (size_t)bb * VAL * DD;
        _Float16*    dst = vsT + (size_t)bb * DD * VAL;
        int b0 = gx * 32;                 // d tile
        for (int vt = 0; vt < 4; ++vt) {
            int a0 = vt * 32;             // v tile
            __syncthreads();
            #pragma unroll
            for (int r = 0; r < 4; ++r)
                tile[ty + r*8][tx] = src[(size_t)(a0 + ty + r*8) * DD + b0 + tx];
            __syncthreads();
            #pragma unroll
            for (int r = 0; r < 4; ++r) {
                int el = ty + r*8;
                dst[(size_t)(b0 + el) * VAL + a0 + tx] = (_Float16)tile[tx][el];
            }
        }
    }
}

// ---------------- fused GEMM: h=relu((q*k)@W1+b1); emit s-partials + masked colsums
// grid (BQ, 2); block 512 = 8 waves as 2m x 4n of 64x64. Tile 128 rows x 256 e-cols.
// BARRIER-FREE K-loop: A fragments built in registers (q*k on the fly), B fragments
// loaded direct from global (L2-hot W1T). No LDS staging -> no convoy.
__global__ __launch_bounds__(512, 4) void gemm_h_kernel(
    const float* __restrict__ qs1,
    const float* __restrict__ ks,
    const int*   __restrict__ sgmask,
    const _Float16* __restrict__ W1T,   // [e][d] fp16
    const float* __restrict__ b1,
    const float* __restrict__ W2,
    float* __restrict__ s_part,         // [BQ][2][VAL]
    float* __restrict__ meansum)        // [BQ][DD]
{
    __shared__ float qrow[DD];
    __shared__ float sred[4][VAL];
    __shared__ float msumLDS[2][256];

    const int tid  = threadIdx.x;
    const int bq   = blockIdx.x;
    const int gy   = blockIdx.y;          // e-half: cols [gy*256, gy*256+256)
    const int b    = bq >> 7;
    const int lane = tid & 63;
    const int wid  = tid >> 6;            // 0..7
    const int wm   = wid >> 2;            // 0..1 (rows wm*64)
    const int wn   = wid & 3;             // 0..3 (cols wn*64)
    const int quad = lane >> 4;
    const int lr   = lane & 15;

    if (tid < 128)
        *(f32x4*)(qrow + tid * 4) = *(const f32x4*)(qs1 + (size_t)bq * DD + tid * 4);

    f32x4 acc[4][4];
    #pragma unroll
    for (int i = 0; i < 4; ++i)
        #pragma unroll
        for (int j = 0; j < 4; ++j) acc[i][j] = (f32x4){0.f, 0.f, 0.f, 0.f};

    // A-operand source rows (ks) and B-operand rows (W1T), fragment-aligned:
    // MFMA A[m=lr][k=quad*8+j], B[k=quad*8+j][n=lr]. Per-step offsets are
    // +kk immediates on these fixed bases (kk*4B <= 1920, kk*2B <= 960).
    const float* kbase[4];
    #pragma unroll
    for (int mt = 0; mt < 4; ++mt)
        kbase[mt] = ks + ((size_t)b * VAL + wm*64 + mt*16 + lr) * DD + quad * 8;
    const _Float16* wbase[4];
    #pragma unroll
    for (int nt = 0; nt < 4; ++nt)
        wbase[nt] = W1T + (size_t)(gy*256 + wn*64 + nt*16 + lr) * DD + quad * 8;
    const float* qb = qrow + quad * 8;
    __syncthreads();   // qrow ready — the ONLY barrier before the epilogue

    #pragma unroll
    for (int kk = 0; kk < DD; kk += BK) {
        f32x4 qv0 = *(const f32x4*)(qb + kk);        // LDS broadcast (16 lanes/addr)
        f32x4 qv1 = *(const f32x4*)(qb + kk + 4);
        f16x8 fa[4];
        #pragma unroll
        for (int mt = 0; mt < 4; ++mt) {
            f32x4 kv0 = *(const f32x4*)(kbase[mt] + kk);
            f32x4 kv1 = *(const f32x4*)(kbase[mt] + kk + 4);
            #pragma unroll
            for (int c = 0; c < 4; ++c) {
                fa[mt][c]     = (_Float16)(kv0[c] * qv0[c]);
                fa[mt][c + 4] = (_Float16)(kv1[c] * qv1[c]);
            }
        }
        #pragma unroll
        for (int nt = 0; nt < 4; ++nt) {
            f16x8 fb = *(const f16x8*)(wbase[nt] + kk);
            #pragma unroll
            for (int mt = 0; mt < 4; ++mt)
                acc[mt][nt] = __builtin_amdgcn_mfma_f32_16x16x32_f16(fa[mt], fb, acc[mt][nt], 0, 0, 0);
        }
    }

    // ---- fused epilogue: C/D layout col=lr (e), row=quad*4+reg (v)
    float b1v[4], w2v[4];
    #pragma unroll
    for (int nt = 0; nt < 4; ++nt) {
        int col = gy*256 + wn*64 + nt*16 + lr;
        b1v[nt] = b1[col];
        w2v[nt] = W2[col];
    }
    float msum[4] = {0.f, 0.f, 0.f, 0.f};
    #pragma unroll
    for (int mt = 0; mt < 4; ++mt) {
        #pragma unroll
        for (int reg = 0; reg < 4; ++reg) {
            int v = wm*64 + mt*16 + quad*4 + reg;
            int masked = sgmask[b * VAL + v];
            float sacc = 0.f;
            #pragma unroll
            for (int nt = 0; nt < 4; ++nt) {
                float h = acc[mt][nt][reg] + b1v[nt];
                h = fmaxf(h, 0.f);
                sacc += h * w2v[nt];
                if (!masked) msum[nt] += h;
            }
            sacc += __shfl_xor(sacc, 1);
            sacc += __shfl_xor(sacc, 2);
            sacc += __shfl_xor(sacc, 4);
            sacc += __shfl_xor(sacc, 8);
            if (lr == 0) sred[wn][v] = sacc;
        }
    }
    #pragma unroll
    for (int nt = 0; nt < 4; ++nt) {
        float m = msum[nt];
        m += __shfl_xor(m, 16);
        m += __shfl_xor(m, 32);
        if (lane < 16) msumLDS[wm][wn*64 + nt*16 + lr] = m;
    }
    __syncthreads();
    if (tid < 128) {
        s_part[((size_t)bq * 2 + gy) * VAL + tid] =
            sred[0][tid] + sred[1][tid] + sred[2][tid] + sred[3][tid];
    } else if (tid >= 256) {
        int c = tid - 256;
        meansum[(size_t)bq * DD + gy*256 + c] = msumLDS[0][c] + msumLDS[1][c];
    }
}

// ---------------- mid: per-bq masked softmax -> wH (1/se folded), meanH (1/denom)
__global__ __launch_bounds__(64) void mid_kernel(
    const float* __restrict__ s_part,     // [BQ][2][VAL]
    const float* __restrict__ meansum,    // [BQ][DD]
    const int*   __restrict__ sgmask,
    const float* __restrict__ b2,
    _Float16* __restrict__ wH,            // [BQ][VAL]
    _Float16* __restrict__ meanH)         // [BQ][DD]
{
    const int bq = blockIdx.x;
    const int b  = bq >> 7;
    const int lane = threadIdx.x;
    const float* sp = s_part + (size_t)bq * 2 * VAL;
    float s0 = fmaxf(sp[lane]      + sp[128 + lane]      + b2[0], 0.f);
    float s1 = fmaxf(sp[64 + lane] + sp[192 + lane]      + b2[0], 0.f);
    int m0 = sgmask[b * VAL + lane], m1 = sgmask[b * VAL + 64 + lane];
    float cnt = (m0 ? 0.f : 1.f) + (m1 ? 0.f : 1.f);
    if (m0) s0 = -1e9f;
    if (m1) s1 = -1e9f;
    float mx = fmaxf(s0, s1);
    #pragma unroll
    for (int off = 32; off; off >>= 1) mx = fmaxf(mx, __shfl_xor(mx, off));
    float e0 = __expf(s0 - mx), e1 = __expf(s1 - mx);
    float se = e0 + e1;
    #pragma unroll
    for (int off = 32; off; off >>= 1) {
        se  += __shfl_xor(se, off);
        cnt += __shfl_xor(cnt, off);
    }
    float invse = 1.f / se;
    float invd  = 1.f / cnt;
    wH[(size_t)bq * VAL + lane]      = (_Float16)(e0 * invse);
    wH[(size_t)bq * VAL + 64 + lane] = (_Float16)(e1 * invse);
    // meanH: 8 elems per lane
    f32x4 mA = *(const f32x4*)(meansum + (size_t)bq * DD + lane * 8);
    f32x4 mB = *(const f32x4*)(meansum + (size_t)bq * DD + lane * 8 + 4);
    f16x8 mh;
    #pragma unroll
    for (int c = 0; c < 4; ++c) {
        mh[c]     = (_Float16)(mA[c] * invd);
        mh[c + 4] = (_Float16)(mB[c] * invd);
    }
    *(f16x8*)(meanH + (size_t)bq * DD + lane * 8) = mh;
}

// ---------------- final: gate = sigmoid(relu(meanH@WseT + bse)); out = gate*(wH@vsT)
// grid (16 q-tiles of 32, 8 d-tiles of 64), 1 wave. Direct-from-global MFMA frags.
__global__ __launch_bounds__(64) void final_kernel(
    const _Float16* __restrict__ meanH,   // [BQ][DD]
    const _Float16* __restrict__ WseT,    // [d][e] fp16
    const _Float16* __restrict__ wH,      // [BQ][VAL]
    const _Float16* __restrict__ vsT,     // [b][d][v] fp16
    const float* __restrict__ bse,
    float* __restrict__ out)              // [BQ][DD]
{
    const int lane = threadIdx.x;
    const int lr   = lane & 15;
    const int quad = lane >> 4;
    const int q0   = blockIdx.x * 32;
    const int d0   = blockIdx.y * 64;
    const int b    = q0 >> 7;

    f32x4 ga[2][4], oa[2][4];
    #pragma unroll
    for (int i = 0; i < 2; ++i)
        #pragma unroll
        for (int j = 0; j < 4; ++j) { ga[i][j] = (f32x4){0,0,0,0}; oa[i][j] = (f32x4){0,0,0,0}; }

    // gate GEMM: K = 512 (e)
    const _Float16* ap0 = meanH + (size_t)(q0 + lr) * DD + quad * 8;
    const _Float16* bp0 = WseT  + (size_t)(d0 + lr) * DD + quad * 8;
    #pragma unroll 2
    for (int kk = 0; kk < DD; kk += 32) {
        f16x8 am[2];
        #pragma unroll
        for (int mt = 0; mt < 2; ++mt)
            am[mt] = *(const f16x8*)(ap0 + (size_t)mt * 16 * DD + kk);
        #pragma unroll
        for (int nt = 0; nt < 4; ++nt) {
            f16x8 bw = *(const f16x8*)(bp0 + (size_t)nt * 16 * DD + kk);
            #pragma unroll
            for (int mt = 0; mt < 2; ++mt)
                ga[mt][nt] = __builtin_amdgcn_mfma_f32_16x16x32_f16(am[mt], bw, ga[mt][nt], 0, 0, 0);
        }
    }
    // out GEMM: K = 128 (v)
    const _Float16* wp0 = wH  + (size_t)(q0 + lr) * VAL + quad * 8;
    const _Float16* vp0 = vsT + (size_t)b * DD * VAL + (size_t)(d0 + lr) * VAL + quad * 8;
    #pragma unroll
    for (int kk = 0; kk < VAL; kk += 32) {
        f16x8 am[2];
        #pragma unroll
        for (int mt = 0; mt < 2; ++mt)
            am[mt] = *(const f16x8*)(wp0 + (size_t)mt * 16 * VAL + kk);
        #pragma unroll
        for (int nt = 0; nt < 4; ++nt) {
            f16x8 bv = *(const f16x8*)(vp0 + (size_t)nt * 16 * VAL + kk);
            #pragma unroll
            for (int mt = 0; mt < 2; ++mt)
                oa[mt][nt] = __builtin_amdgcn_mfma_f32_16x16x32_f16(am[mt], bv, oa[mt][nt], 0, 0, 0);
        }
    }
    // epilogue: C/D col=lr, row=quad*4+reg
    #pragma unroll
    for (int nt = 0; nt < 4; ++nt) {
        int col = d0 + nt * 16 + lr;
        float bsev = bse[col];
        #pragma unroll
        for (int mt = 0; mt < 2; ++mt) {
            #pragma unroll
            for (int reg = 0; reg < 4; ++reg) {
                int row = q0 + mt * 16 + quad * 4 + reg;
                float garg = ga[mt][nt][reg] + bsev;
                garg = fmaxf(garg, 0.f);
                float gate = 1.f / (1.f + __expf(-garg));
                out[(size_t)row * DD + col] = gate * oa[mt][nt][reg];
            }
        }
    }
}

extern "C" void kernel_launch(void* const* d_in, const int* in_sizes, int n_in,
                              void* d_out, int out_size, void* d_ws, size_t ws_size,
                              hipStream_t stream) {
    (void)in_sizes; (void)n_in; (void)out_size; (void)ws_size;
    const float* qs1 = (const float*)d_in[0];
    const float* ks  = (const float*)d_in[2];
    const float* vs  = (const float*)d_in[3];
    const int*   sg  = (const int*)d_in[4];
    const float* W1  = (const float*)d_in[5];
    const float* b1  = (const float*)d_in[6];
    const float* Wse = (const float*)d_in[7];
    const float* bse = (const float*)d_in[8];
    const float* W2  = (const float*)d_in[9];
    const float* b2  = (const float*)d_in[10];
    float* out = (float*)d_out;

    char* ws = (char*)d_ws;
    _Float16* W1T    = (_Float16*)(ws);                        // 512 KB
    _Float16* WseT   = (_Float16*)(ws + (512 << 10));          // 512 KB
    _Float16* vsT    = (_Float16*)(ws + (1 << 20));            // 512 KB
    float*    s_part = (float*)(ws + (1536 << 10));            // 512 KB
    float*    msum   = (float*)(ws + (2 << 20));               // 1 MB
    _Float16* wH     = (_Float16*)(ws + (3 << 20));            // 128 KB
    _Float16* meanH  = (_Float16*)(ws + (3 << 20) + (128 << 10)); // 512 KB

    prep_kernel<<<dim3(16, 36), 256, 0, stream>>>(W1, W1T, Wse, WseT, vs, vsT);
    gemm_h_kernel<<<dim3(BQ, 2), 512, 0, stream>>>(qs1, ks, sg, W1T, b1, W2, s_part, msum);
    mid_kernel<<<BQ, 64, 0, stream>>>(s_part, msum, sg, b2, wH, meanH);
    final_kernel<<<dim3(16, 8), 64, 0, stream>>>(meanH, WseT, wH, vsT, bse, out);
}

// Round 8
// 133.981 us; speedup vs baseline: 2.0271x; 2.0271x over previous
//
#include <hip/hip_runtime.h>
#include <stdint.h>
#include <stddef.h>

#define BDIM 4
#define QUE  128
#define VAL  128
#define DD   512
#define BQ   (BDIM*QUE)
#define BK   64
// 8 slots of 8 f16 (16B) per row; true kseg c stored at slot (c + (r&7)) & 7

typedef float    f32x4 __attribute__((ext_vector_type(4)));
typedef float    f32x2 __attribute__((ext_vector_type(2)));
typedef _Float16 f16x8 __attribute__((ext_vector_type(8)));
typedef _Float16 f16x4 __attribute__((ext_vector_type(4)));
typedef _Float16 f16x2 __attribute__((ext_vector_type(2)));

typedef const __attribute__((address_space(1))) void* gas_ptr;
typedef __attribute__((address_space(3))) void*       las_ptr;

__device__ __forceinline__ void async_copy16(const void* g, void* l) {
    __builtin_amdgcn_global_load_lds((gas_ptr)g, (las_ptr)l, 16, 0, 0);
}

// ---------------- prep: fp16 transposes  W1->W1T[e][d], Wse->WseT[d][e],
//                  vs->vsT[b][d][v] -------------------------------------------
__global__ __launch_bounds__(256) void prep_kernel(const float* __restrict__ W1,
                                                   _Float16* __restrict__ W1T,
                                                   const float* __restrict__ Wse,
                                                   _Float16* __restrict__ WseT,
                                                   const float* __restrict__ vs,
                                                   _Float16* __restrict__ vsT) {
    __shared__ float tile[32][33];
    const int tx = threadIdx.x & 31;
    const int ty = threadIdx.x >> 5;      // 0..7
    const int gx = blockIdx.x, gy = blockIdx.y;
    if (gy < 32) {
        const float* src = (gy < 16) ? W1  : Wse;
        _Float16*    dst = (gy < 16) ? W1T : WseT;
        int a0 = gx * 32;                 // source-row tile
        int b0 = (gy & 15) * 32;          // source-col tile
        #pragma unroll
        for (int r = 0; r < 4; ++r)
            tile[ty + r*8][tx] = src[(size_t)(a0 + ty + r*8) * DD + b0 + tx];
        __syncthreads();
        #pragma unroll
        for (int r = 0; r < 4; ++r) {
            int el = ty + r*8;
            dst[(size_t)(b0 + el) * DD + a0 + tx] = (_Float16)tile[tx][el];
        }
    } else {
        // vs[b][v][d] -> vsT[b][d][v], b = gy-32, d-tile = gx
        int bb = gy - 32;
        const float* src = vs  + (size_t)bb * VAL * DD;
        _Float16*    dst = vsT + (size_t)bb * DD * VAL;
        int b0 = gx * 32;                 // d tile
        for (int vt = 0; vt < 4; ++vt) {
            int a0 = vt * 32;             // v tile
            __syncthreads();
            #pragma unroll
            for (int r = 0; r < 4; ++r)
                tile[ty + r*8][tx] = src[(size_t)(a0 + ty + r*8) * DD + b0 + tx];
            __syncthreads();
            #pragma unroll
            for (int r = 0; r < 4; ++r) {
                int el = ty + r*8;
                dst[(size_t)(b0 + el) * VAL + a0 + tx] = (_Float16)tile[tx][el];
            }
        }
    }
}

// ---------------- fused GEMM: h=relu((q*k)@W1+b1); emit s-partials + masked colsums
// grid (BQ, 2); block 512 = 8 waves as 2m x 4n of 64x64. Tile 128 rows x 256 e-cols.
// BK=64: 16 barriers total (vs 32 at BK=32) — amortizes the vmcnt(0) barrier drain.
__global__ __launch_bounds__(512, 4) void gemm_h_kernel(
    const float* __restrict__ qs1,
    const float* __restrict__ ks,
    const int*   __restrict__ sgmask,
    const _Float16* __restrict__ W1T,   // [e][d] fp16
    const float* __restrict__ b1,
    const float* __restrict__ W2,
    float* __restrict__ s_part,         // [BQ][2][VAL]
    float* __restrict__ meansum)        // [BQ][DD]
{
    __shared__ _Float16 Ah[128 * BK];     // x tile   [v][k]  16 KB
    __shared__ _Float16 Bh[256 * BK];     // W1T tile [e][k]  32 KB
    __shared__ float qrow[DD];
    __shared__ float sred[4][VAL];
    __shared__ float msumLDS[2][256];

    const int tid  = threadIdx.x;
    const int bq   = blockIdx.x;
    const int gy   = blockIdx.y;          // e-half: cols [gy*256, gy*256+256)
    const int b    = bq >> 7;
    const int lane = tid & 63;
    const int wid  = tid >> 6;            // 0..7
    const int wm   = wid >> 2;            // 0..1 (rows wm*64)
    const int wn   = wid & 3;             // 0..3 (cols wn*64)
    const int quad = lane >> 4;
    const int lr   = lane & 15;

    if (tid < 128)
        *(f32x4*)(qrow + tid * 4) = *(const f32x4*)(qs1 + (size_t)bq * DD + tid * 4);

    f32x4 acc[4][4];
    #pragma unroll
    for (int i = 0; i < 4; ++i)
        #pragma unroll
        for (int j = 0; j < 4; ++j) acc[i][j] = (f32x4){0.f, 0.f, 0.f, 0.f};

    // ---- A staging: 2 chunks/thread (chunk = tid, tid+512); chunk -> row=c>>3, slot=c&7
    const int ar0 = tid >> 3;             // chunk tid   -> row 0..63
    const int ar1 = 64 + ar0;             // chunk tid+512 -> row 64..127
    const int slt = tid & 7;
    const int ca0 = (slt - (ar0 & 7)) & 7;   // true kseg
    const int ca1 = (slt - (ar1 & 7)) & 7;   // == ca0 (rows differ by 64) but keep general
    const float* ksrow0 = ks + ((size_t)b * VAL + ar0) * DD + ca0 * 8;
    const float* ksrow1 = ks + ((size_t)b * VAL + ar1) * DD + ca1 * 8;
    const float* qb0 = qrow + ca0 * 8;
    const float* qb1 = qrow + ca1 * 8;
    const int aoff0 = tid * 8;            // chunk*8 f16 == row*BK + slot*8
    const int aoff1 = (512 + tid) * 8;

    // ---- B staging: 4 asyncs/thread; async j covers chunks j*512 + tid ----
    const _Float16* gB[4];
    int ldsBoff[4];                       // f16 units, wave-uniform + lane*16B implicit
    #pragma unroll
    for (int j = 0; j < 4; ++j) {
        int chunk = j * 512 + tid;
        int row   = chunk >> 3;           // 0..255
        int c     = ((chunk & 7) - (row & 7)) & 7;
        gB[j] = W1T + (size_t)(gy * 256 + row) * DD + c * 8;
        ldsBoff[j] = (j * 512 + wid * 64) * 8;   // wave-uniform chunk base * 8 f16
    }

    // ---- fragment offsets (f16 units); sub-step 1 = offset XOR 32 (slot+4 mod 8) ----
    int faoff[4], fboff[4];
    #pragma unroll
    for (int mt = 0; mt < 4; ++mt) {
        int row = wm * 64 + mt * 16 + lr;
        faoff[mt] = row * BK + (((quad + row) & 7) << 3);
    }
    #pragma unroll
    for (int nt = 0; nt < 4; ++nt) {
        int row = wn * 64 + nt * 16 + lr;
        fboff[nt] = row * BK + (((quad + row) & 7) << 3);
    }
    __syncthreads();   // qrow ready

    for (int kk = 0; kk < DD; kk += BK) {
        // ---- B: 4 async global->LDS (16 B/lane, swizzled source kseg)
        #pragma unroll
        for (int j = 0; j < 4; ++j)
            async_copy16(gB[j] + kk, &Bh[ldsBoff[j]]);
        // ---- A: x = q*k, fp32->fp16 RNE, two b128 writes
        {
            f32x4 kv0 = *(const f32x4*)(ksrow0 + kk);
            f32x4 kv1 = *(const f32x4*)(ksrow0 + kk + 4);
            f32x4 qv0 = *(const f32x4*)(qb0 + kk);
            f32x4 qv1 = *(const f32x4*)(qb0 + kk + 4);
            f16x8 av;
            #pragma unroll
            for (int c = 0; c < 4; ++c) {
                av[c]     = (_Float16)(kv0[c] * qv0[c]);
                av[c + 4] = (_Float16)(kv1[c] * qv1[c]);
            }
            *(f16x8*)&Ah[aoff0] = av;
        }
        {
            f32x4 kv0 = *(const f32x4*)(ksrow1 + kk);
            f32x4 kv1 = *(const f32x4*)(ksrow1 + kk + 4);
            f32x4 qv0 = *(const f32x4*)(qb1 + kk);
            f32x4 qv1 = *(const f32x4*)(qb1 + kk + 4);
            f16x8 av;
            #pragma unroll
            for (int c = 0; c < 4; ++c) {
                av[c]     = (_Float16)(kv0[c] * qv0[c]);
                av[c + 4] = (_Float16)(kv1[c] * qv1[c]);
            }
            *(f16x8*)&Ah[aoff1] = av;
        }
        __syncthreads();

        // ---- MFMA: two K=32 sub-steps; sub-step toggles slot by XOR 32 f16
        #pragma unroll
        for (int sub = 0; sub < 2; ++sub) {
            const int sx = sub << 5;      // 0 or 32 f16
            f16x8 fa[4];
            #pragma unroll
            for (int mt = 0; mt < 4; ++mt)
                fa[mt] = *(const f16x8*)&Ah[faoff[mt] ^ sx];
            #pragma unroll
            for (int nt = 0; nt < 4; ++nt) {
                f16x8 fb = *(const f16x8*)&Bh[fboff[nt] ^ sx];
                #pragma unroll
                for (int mt = 0; mt < 4; ++mt)
                    acc[mt][nt] = __builtin_amdgcn_mfma_f32_16x16x32_f16(fa[mt], fb, acc[mt][nt], 0, 0, 0);
            }
        }
        __syncthreads();
    }

    // ---- fused epilogue: C/D layout col=lr (e), row=quad*4+reg (v)
    float b1v[4], w2v[4];
    #pragma unroll
    for (int nt = 0; nt < 4; ++nt) {
        int col = gy*256 + wn*64 + nt*16 + lr;
        b1v[nt] = b1[col];
        w2v[nt] = W2[col];
    }
    float msum[4] = {0.f, 0.f, 0.f, 0.f};
    #pragma unroll
    for (int mt = 0; mt < 4; ++mt) {
        #pragma unroll
        for (int reg = 0; reg < 4; ++reg) {
            int v = wm*64 + mt*16 + quad*4 + reg;
            int masked = sgmask[b * VAL + v];
            float sacc = 0.f;
            #pragma unroll
            for (int nt = 0; nt < 4; ++nt) {
                float h = acc[mt][nt][reg] + b1v[nt];
                h = fmaxf(h, 0.f);
                sacc += h * w2v[nt];
                if (!masked) msum[nt] += h;
            }
            sacc += __shfl_xor(sacc, 1);
            sacc += __shfl_xor(sacc, 2);
            sacc += __shfl_xor(sacc, 4);
            sacc += __shfl_xor(sacc, 8);
            if (lr == 0) sred[wn][v] = sacc;
        }
    }
    #pragma unroll
    for (int nt = 0; nt < 4; ++nt) {
        float m = msum[nt];
        m += __shfl_xor(m, 16);
        m += __shfl_xor(m, 32);
        if (lane < 16) msumLDS[wm][wn*64 + nt*16 + lr] = m;
    }
    __syncthreads();
    if (tid < 128) {
        s_part[((size_t)bq * 2 + gy) * VAL + tid] =
            sred[0][tid] + sred[1][tid] + sred[2][tid] + sred[3][tid];
    } else if (tid >= 256) {
        int c = tid - 256;
        meansum[(size_t)bq * DD + gy*256 + c] = msumLDS[0][c] + msumLDS[1][c];
    }
}

// ---------------- mid: per-bq masked softmax -> wH (1/se folded), meanH (1/denom)
__global__ __launch_bounds__(64) void mid_kernel(
    const float* __restrict__ s_part,     // [BQ][2][VAL]
    const float* __restrict__ meansum,    // [BQ][DD]
    const int*   __restrict__ sgmask,
    const float* __restrict__ b2,
    _Float16* __restrict__ wH,            // [BQ][VAL]
    _Float16* __restrict__ meanH)         // [BQ][DD]
{
    const int bq = blockIdx.x;
    const int b  = bq >> 7;
    const int lane = threadIdx.x;
    const float* sp = s_part + (size_t)bq * 2 * VAL;
    float s0 = fmaxf(sp[lane]      + sp[128 + lane]      + b2[0], 0.f);
    float s1 = fmaxf(sp[64 + lane] + sp[192 + lane]      + b2[0], 0.f);
    int m0 = sgmask[b * VAL + lane], m1 = sgmask[b * VAL + 64 + lane];
    float cnt = (m0 ? 0.f : 1.f) + (m1 ? 0.f : 1.f);
    if (m0) s0 = -1e9f;
    if (m1) s1 = -1e9f;
    float mx = fmaxf(s0, s1);
    #pragma unroll
    for (int off = 32; off; off >>= 1) mx = fmaxf(mx, __shfl_xor(mx, off));
    float e0 = __expf(s0 - mx), e1 = __expf(s1 - mx);
    float se = e0 + e1;
    #pragma unroll
    for (int off = 32; off; off >>= 1) {
        se  += __shfl_xor(se, off);
        cnt += __shfl_xor(cnt, off);
    }
    float invse = 1.f / se;
    float invd  = 1.f / cnt;
    wH[(size_t)bq * VAL + lane]      = (_Float16)(e0 * invse);
    wH[(size_t)bq * VAL + 64 + lane] = (_Float16)(e1 * invse);
    // meanH: 8 elems per lane
    f32x4 mA = *(const f32x4*)(meansum + (size_t)bq * DD + lane * 8);
    f32x4 mB = *(const f32x4*)(meansum + (size_t)bq * DD + lane * 8 + 4);
    f16x8 mh;
    #pragma unroll
    for (int c = 0; c < 4; ++c) {
        mh[c]     = (_Float16)(mA[c] * invd);
        mh[c + 4] = (_Float16)(mB[c] * invd);
    }
    *(f16x8*)(meanH + (size_t)bq * DD + lane * 8) = mh;
}

// ---------------- final: gate = sigmoid(relu(meanH@WseT + bse)); out = gate*(wH@vsT)
// grid (16 q-tiles of 32, 8 d-tiles of 64), 1 wave. Direct-from-global MFMA frags.
__global__ __launch_bounds__(64) void final_kernel(
    const _Float16* __restrict__ meanH,   // [BQ][DD]
    const _Float16* __restrict__ WseT,    // [d][e] fp16
    const _Float16* __restrict__ wH,      // [BQ][VAL]
    const _Float16* __restrict__ vsT,     // [b][d][v] fp16
    const float* __restrict__ bse,
    float* __restrict__ out)              // [BQ][DD]
{
    const int lane = threadIdx.x;
    const int lr   = lane & 15;
    const int quad = lane >> 4;
    const int q0   = blockIdx.x * 32;
    const int d0   = blockIdx.y * 64;
    const int b    = q0 >> 7;

    f32x4 ga[2][4], oa[2][4];
    #pragma unroll
    for (int i = 0; i < 2; ++i)
        #pragma unroll
        for (int j = 0; j < 4; ++j) { ga[i][j] = (f32x4){0,0,0,0}; oa[i][j] = (f32x4){0,0,0,0}; }

    // gate GEMM: K = 512 (e)
    const _Float16* ap0 = meanH + (size_t)(q0 + lr) * DD + quad * 8;
    const _Float16* bp0 = WseT  + (size_t)(d0 + lr) * DD + quad * 8;
    #pragma unroll 2
    for (int kk = 0; kk < DD; kk += 32) {
        f16x8 am[2];
        #pragma unroll
        for (int mt = 0; mt < 2; ++mt)
            am[mt] = *(const f16x8*)(ap0 + (size_t)mt * 16 * DD + kk);
        #pragma unroll
        for (int nt = 0; nt < 4; ++nt) {
            f16x8 bw = *(const f16x8*)(bp0 + (size_t)nt * 16 * DD + kk);
            #pragma unroll
            for (int mt = 0; mt < 2; ++mt)
                ga[mt][nt] = __builtin_amdgcn_mfma_f32_16x16x32_f16(am[mt], bw, ga[mt][nt], 0, 0, 0);
        }
    }
    // out GEMM: K = 128 (v)
    const _Float16* wp0 = wH  + (size_t)(q0 + lr) * VAL + quad * 8;
    const _Float16* vp0 = vsT + (size_t)b * DD * VAL + (size_t)(d0 + lr) * VAL + quad * 8;
    #pragma unroll
    for (int kk = 0; kk < VAL; kk += 32) {
        f16x8 am[2];
        #pragma unroll
        for (int mt = 0; mt < 2; ++mt)
            am[mt] = *(const f16x8*)(wp0 + (size_t)mt * 16 * VAL + kk);
        #pragma unroll
        for (int nt = 0; nt < 4; ++nt) {
            f16x8 bv = *(const f16x8*)(vp0 + (size_t)nt * 16 * VAL + kk);
            #pragma unroll
            for (int mt = 0; mt < 2; ++mt)
                oa[mt][nt] = __builtin_amdgcn_mfma_f32_16x16x32_f16(am[mt], bv, oa[mt][nt], 0, 0, 0);
        }
    }
    // epilogue: C/D col=lr, row=quad*4+reg
    #pragma unroll
    for (int nt = 0; nt < 4; ++nt) {
        int col = d0 + nt * 16 + lr;
        float bsev = bse[col];
        #pragma unroll
        for (int mt = 0; mt < 2; ++mt) {
            #pragma unroll
            for (int reg = 0; reg < 4; ++reg) {
                int row = q0 + mt * 16 + quad * 4 + reg;
                float garg = ga[mt][nt][reg] + bsev;
                garg = fmaxf(garg, 0.f);
                float gate = 1.f / (1.f + __expf(-garg));
                out[(size_t)row * DD + col] = gate * oa[mt][nt][reg];
            }
        }
    }
}

extern "C" void kernel_launch(void* const* d_in, const int* in_sizes, int n_in,
                              void* d_out, int out_size, void* d_ws, size_t ws_size,
                              hipStream_t stream) {
    (void)in_sizes; (void)n_in; (void)out_size; (void)ws_size;
    const float* qs1 = (const float*)d_in[0];
    const float* ks  = (const float*)d_in[2];
    const float* vs  = (const float*)d_in[3];
    const int*   sg  = (const int*)d_in[4];
    const float* W1  = (const float*)d_in[5];
    const float* b1  = (const float*)d_in[6];
    const float* Wse = (const float*)d_in[7];
    const float* bse = (const float*)d_in[8];
    const float* W2  = (const float*)d_in[9];
    const float* b2  = (const float*)d_in[10];
    float* out = (float*)d_out;

    char* ws = (char*)d_ws;
    _Float16* W1T    = (_Float16*)(ws);                        // 512 KB
    _Float16* WseT   = (_Float16*)(ws + (512 << 10));          // 512 KB
    _Float16* vsT    = (_Float16*)(ws + (1 << 20));            // 512 KB
    float*    s_part = (float*)(ws + (1536 << 10));            // 512 KB
    float*    msum   = (float*)(ws + (2 << 20));               // 1 MB
    _Float16* wH     = (_Float16*)(ws + (3 << 20));            // 128 KB
    _Float16* meanH  = (_Float16*)(ws + (3 << 20) + (128 << 10)); // 512 KB

    prep_kernel<<<dim3(16, 36), 256, 0, stream>>>(W1, W1T, Wse, WseT, vs, vsT);
    gemm_h_kernel<<<dim3(BQ, 2), 512, 0, stream>>>(qs1, ks, sg, W1T, b1, W2, s_part, msum);
    mid_kernel<<<BQ, 64, 0, stream>>>(s_part, msum, sg, b2, wH, meanH);
    final_kernel<<<dim3(16, 8), 64, 0, stream>>>(meanH, WseT, wH, vsT, bse, out);
}

// Round 9
// 131.937 us; speedup vs baseline: 2.0585x; 1.0155x over previous
//
#include <hip/hip_runtime.h>
#include <stdint.h>
#include <stddef.h>

#define BDIM 4
#define QUE  128
#define VAL  128
#define DD   512
#define BQ   (BDIM*QUE)
#define BK   64
// gemm LDS: 8 slots of 8 f16 (16B) per row; true kseg c stored at slot (c + (r&7)) & 7

typedef float    f32x4 __attribute__((ext_vector_type(4)));
typedef float    f32x2 __attribute__((ext_vector_type(2)));
typedef _Float16 f16x8 __attribute__((ext_vector_type(8)));
typedef _Float16 f16x4 __attribute__((ext_vector_type(4)));
typedef _Float16 f16x2 __attribute__((ext_vector_type(2)));

typedef const __attribute__((address_space(1))) void* gas_ptr;
typedef __attribute__((address_space(3))) void*       las_ptr;

__device__ __forceinline__ void async_copy16(const void* g, void* l) {
    __builtin_amdgcn_global_load_lds((gas_ptr)g, (las_ptr)l, 16, 0, 0);
}

// ---------------- prep: fp16 transposes  W1->W1T[e][d], Wse->WseT[d][e],
//                  vs->vsT[b][d][v] -------------------------------------------
__global__ __launch_bounds__(256) void prep_kernel(const float* __restrict__ W1,
                                                   _Float16* __restrict__ W1T,
                                                   const float* __restrict__ Wse,
                                                   _Float16* __restrict__ WseT,
                                                   const float* __restrict__ vs,
                                                   _Float16* __restrict__ vsT) {
    __shared__ float tile[32][33];
    const int tx = threadIdx.x & 31;
    const int ty = threadIdx.x >> 5;      // 0..7
    const int gx = blockIdx.x, gy = blockIdx.y;
    if (gy < 32) {
        const float* src = (gy < 16) ? W1  : Wse;
        _Float16*    dst = (gy < 16) ? W1T : WseT;
        int a0 = gx * 32;                 // source-row tile
        int b0 = (gy & 15) * 32;          // source-col tile
        #pragma unroll
        for (int r = 0; r < 4; ++r)
            tile[ty + r*8][tx] = src[(size_t)(a0 + ty + r*8) * DD + b0 + tx];
        __syncthreads();
        #pragma unroll
        for (int r = 0; r < 4; ++r) {
            int el = ty + r*8;
            dst[(size_t)(b0 + el) * DD + a0 + tx] = (_Float16)tile[tx][el];
        }
    } else {
        // vs[b][v][d] -> vsT[b][d][v], b = gy-32, d-tile = gx
        int bb = gy - 32;
        const float* src = vs  + (size_t)bb * VAL * DD;
        _Float16*    dst = vsT + (size_t)bb * DD * VAL;
        int b0 = gx * 32;                 // d tile
        for (int vt = 0; vt < 4; ++vt) {
            int a0 = vt * 32;             // v tile
            __syncthreads();
            #pragma unroll
            for (int r = 0; r < 4; ++r)
                tile[ty + r*8][tx] = src[(size_t)(a0 + ty + r*8) * DD + b0 + tx];
            __syncthreads();
            #pragma unroll
            for (int r = 0; r < 4; ++r) {
                int el = ty + r*8;
                dst[(size_t)(b0 + el) * VAL + a0 + tx] = (_Float16)tile[tx][el];
            }
        }
    }
}

// ---------------- fused GEMM: h=relu((q*k)@W1+b1); emit s-partials + masked colsums
// grid (BQ, 2); block 512 = 8 waves as 2m x 4n of 64x64. Tile 128 rows x 256 e-cols.
// BK=64: 16 barriers total — amortizes the vmcnt(0) barrier drain. (r8 winner)
__global__ __launch_bounds__(512, 4) void gemm_h_kernel(
    const float* __restrict__ qs1,
    const float* __restrict__ ks,
    const int*   __restrict__ sgmask,
    const _Float16* __restrict__ W1T,   // [e][d] fp16
    const float* __restrict__ b1,
    const float* __restrict__ W2,
    float* __restrict__ s_part,         // [BQ][2][VAL]
    float* __restrict__ meansum)        // [BQ][DD]
{
    __shared__ _Float16 Ah[128 * BK];     // x tile   [v][k]  16 KB
    __shared__ _Float16 Bh[256 * BK];     // W1T tile [e][k]  32 KB
    __shared__ float qrow[DD];
    __shared__ float sred[4][VAL];
    __shared__ float msumLDS[2][256];

    const int tid  = threadIdx.x;
    const int bq   = blockIdx.x;
    const int gy   = blockIdx.y;          // e-half: cols [gy*256, gy*256+256)
    const int b    = bq >> 7;
    const int lane = tid & 63;
    const int wid  = tid >> 6;            // 0..7
    const int wm   = wid >> 2;            // 0..1 (rows wm*64)
    const int wn   = wid & 3;             // 0..3 (cols wn*64)
    const int quad = lane >> 4;
    const int lr   = lane & 15;

    if (tid < 128)
        *(f32x4*)(qrow + tid * 4) = *(const f32x4*)(qs1 + (size_t)bq * DD + tid * 4);

    f32x4 acc[4][4];
    #pragma unroll
    for (int i = 0; i < 4; ++i)
        #pragma unroll
        for (int j = 0; j < 4; ++j) acc[i][j] = (f32x4){0.f, 0.f, 0.f, 0.f};

    // ---- A staging: 2 chunks/thread (chunk = tid, tid+512); chunk -> row=c>>3, slot=c&7
    const int ar0 = tid >> 3;             // chunk tid   -> row 0..63
    const int ar1 = 64 + ar0;             // chunk tid+512 -> row 64..127
    const int slt = tid & 7;
    const int ca0 = (slt - (ar0 & 7)) & 7;   // true kseg
    const int ca1 = (slt - (ar1 & 7)) & 7;
    const float* ksrow0 = ks + ((size_t)b * VAL + ar0) * DD + ca0 * 8;
    const float* ksrow1 = ks + ((size_t)b * VAL + ar1) * DD + ca1 * 8;
    const float* qb0 = qrow + ca0 * 8;
    const float* qb1 = qrow + ca1 * 8;
    const int aoff0 = tid * 8;            // chunk*8 f16 == row*BK + slot*8
    const int aoff1 = (512 + tid) * 8;

    // ---- B staging: 4 asyncs/thread; async j covers chunks j*512 + tid ----
    const _Float16* gB[4];
    int ldsBoff[4];                       // f16 units, wave-uniform + lane*16B implicit
    #pragma unroll
    for (int j = 0; j < 4; ++j) {
        int chunk = j * 512 + tid;
        int row   = chunk >> 3;           // 0..255
        int c     = ((chunk & 7) - (row & 7)) & 7;
        gB[j] = W1T + (size_t)(gy * 256 + row) * DD + c * 8;
        ldsBoff[j] = (j * 512 + wid * 64) * 8;   // wave-uniform chunk base * 8 f16
    }

    // ---- fragment offsets (f16 units); sub-step 1 = offset XOR 32 (slot+4 mod 8) ----
    int faoff[4], fboff[4];
    #pragma unroll
    for (int mt = 0; mt < 4; ++mt) {
        int row = wm * 64 + mt * 16 + lr;
        faoff[mt] = row * BK + (((quad + row) & 7) << 3);
    }
    #pragma unroll
    for (int nt = 0; nt < 4; ++nt) {
        int row = wn * 64 + nt * 16 + lr;
        fboff[nt] = row * BK + (((quad + row) & 7) << 3);
    }
    __syncthreads();   // qrow ready

    for (int kk = 0; kk < DD; kk += BK) {
        #pragma unroll
        for (int j = 0; j < 4; ++j)
            async_copy16(gB[j] + kk, &Bh[ldsBoff[j]]);
        {
            f32x4 kv0 = *(const f32x4*)(ksrow0 + kk);
            f32x4 kv1 = *(const f32x4*)(ksrow0 + kk + 4);
            f32x4 qv0 = *(const f32x4*)(qb0 + kk);
            f32x4 qv1 = *(const f32x4*)(qb0 + kk + 4);
            f16x8 av;
            #pragma unroll
            for (int c = 0; c < 4; ++c) {
                av[c]     = (_Float16)(kv0[c] * qv0[c]);
                av[c + 4] = (_Float16)(kv1[c] * qv1[c]);
            }
            *(f16x8*)&Ah[aoff0] = av;
        }
        {
            f32x4 kv0 = *(const f32x4*)(ksrow1 + kk);
            f32x4 kv1 = *(const f32x4*)(ksrow1 + kk + 4);
            f32x4 qv0 = *(const f32x4*)(qb1 + kk);
            f32x4 qv1 = *(const f32x4*)(qb1 + kk + 4);
            f16x8 av;
            #pragma unroll
            for (int c = 0; c < 4; ++c) {
                av[c]     = (_Float16)(kv0[c] * qv0[c]);
                av[c + 4] = (_Float16)(kv1[c] * qv1[c]);
            }
            *(f16x8*)&Ah[aoff1] = av;
        }
        __syncthreads();

        #pragma unroll
        for (int sub = 0; sub < 2; ++sub) {
            const int sx = sub << 5;      // 0 or 32 f16
            f16x8 fa[4];
            #pragma unroll
            for (int mt = 0; mt < 4; ++mt)
                fa[mt] = *(const f16x8*)&Ah[faoff[mt] ^ sx];
            #pragma unroll
            for (int nt = 0; nt < 4; ++nt) {
                f16x8 fb = *(const f16x8*)&Bh[fboff[nt] ^ sx];
                #pragma unroll
                for (int mt = 0; mt < 4; ++mt)
                    acc[mt][nt] = __builtin_amdgcn_mfma_f32_16x16x32_f16(fa[mt], fb, acc[mt][nt], 0, 0, 0);
            }
        }
        __syncthreads();
    }

    // ---- fused epilogue: C/D layout col=lr (e), row=quad*4+reg (v)
    float b1v[4], w2v[4];
    #pragma unroll
    for (int nt = 0; nt < 4; ++nt) {
        int col = gy*256 + wn*64 + nt*16 + lr;
        b1v[nt] = b1[col];
        w2v[nt] = W2[col];
    }
    float msum[4] = {0.f, 0.f, 0.f, 0.f};
    #pragma unroll
    for (int mt = 0; mt < 4; ++mt) {
        #pragma unroll
        for (int reg = 0; reg < 4; ++reg) {
            int v = wm*64 + mt*16 + quad*4 + reg;
            int masked = sgmask[b * VAL + v];
            float sacc = 0.f;
            #pragma unroll
            for (int nt = 0; nt < 4; ++nt) {
                float h = acc[mt][nt][reg] + b1v[nt];
                h = fmaxf(h, 0.f);
                sacc += h * w2v[nt];
                if (!masked) msum[nt] += h;
            }
            sacc += __shfl_xor(sacc, 1);
            sacc += __shfl_xor(sacc, 2);
            sacc += __shfl_xor(sacc, 4);
            sacc += __shfl_xor(sacc, 8);
            if (lr == 0) sred[wn][v] = sacc;
        }
    }
    #pragma unroll
    for (int nt = 0; nt < 4; ++nt) {
        float m = msum[nt];
        m += __shfl_xor(m, 16);
        m += __shfl_xor(m, 32);
        if (lane < 16) msumLDS[wm][wn*64 + nt*16 + lr] = m;
    }
    __syncthreads();
    if (tid < 128) {
        s_part[((size_t)bq * 2 + gy) * VAL + tid] =
            sred[0][tid] + sred[1][tid] + sred[2][tid] + sred[3][tid];
    } else if (tid >= 256) {
        int c = tid - 256;
        meansum[(size_t)bq * DD + gy*256 + c] = msumLDS[0][c] + msumLDS[1][c];
    }
}

// ---------------- final (fuses mid): softmax+mean in-block, then two LDS-staged
// mini-GEMMs. grid (16 q-tiles of 32, 16 d-tiles of 32), 256 thr = 4 waves (2m x 2n).
#define MPAD 514   // meanLDS row stride (f16): 257 dwords === 1 mod 32 -> conflict-free
#define WPAD 130   // wLDS/BLDS row stride: 65 dwords === 1 mod 32
__global__ __launch_bounds__(256) void final_kernel(
    const float* __restrict__ s_part,     // [BQ][2][VAL]
    const float* __restrict__ msum,       // [BQ][DD]
    const int*   __restrict__ sgmask,
    const _Float16* __restrict__ WseT,    // [d][e] fp16
    const _Float16* __restrict__ vsT,     // [b][d][v] fp16
    const float* __restrict__ bse,
    const float* __restrict__ b2,
    float* __restrict__ out)              // [BQ][DD]
{
    __shared__ _Float16 meanLDS[32 * MPAD];   // 32.9 KB  A of gate GEMM (all 512 e)
    __shared__ _Float16 wLDS[32 * WPAD];      //  8.3 KB  A of out GEMM
    __shared__ _Float16 BLDS[32 * WPAD];      //  8.3 KB  B chunk (WseT then vsT)

    const int tid  = threadIdx.x;
    const int q0   = blockIdx.x * 32;
    const int d0   = blockIdx.y * 32;
    const int b    = q0 >> 7;                 // whole q-tile within one batch
    const int lane = tid & 63;
    const int wid  = tid >> 6;                // 0..3
    const int wm   = wid >> 1, wn = wid & 1;  // 2m x 2n of 16x16
    const int quad = lane >> 4;
    const int lr   = lane & 15;
    const int r    = tid >> 3;                // 0..31 (row for staging/softmax)
    const int sl   = tid & 7;                 // 0..7  (segment)

    // ---- phase A: softmax over v (8 lanes/row) + mean (fold 1/denom) ----
    const float b2v = b2[0];
    const int   bq  = q0 + r;
    const float* sp = s_part + (size_t)bq * 2 * VAL;
    float vals[16];
    int   msk[16];
    float smax = -3.4e38f;
    #pragma unroll
    for (int i4 = 0; i4 < 4; ++i4) {
        f32x4 s0 = *(const f32x4*)(sp + sl*16 + i4*4);
        f32x4 s1 = *(const f32x4*)(sp + VAL + sl*16 + i4*4);
        #pragma unroll
        for (int j = 0; j < 4; ++j) {
            int idx = i4*4 + j;
            int v   = sl*16 + idx;
            float s = fmaxf(s0[j] + s1[j] + b2v, 0.f);
            int m   = sgmask[b * VAL + v];
            msk[idx] = m;
            if (m) s = -1e9f;
            vals[idx] = s;
            smax = fmaxf(smax, s);
        }
    }
    smax = fmaxf(smax, __shfl_xor(smax, 1));
    smax = fmaxf(smax, __shfl_xor(smax, 2));
    smax = fmaxf(smax, __shfl_xor(smax, 4));
    float sume = 0.f, cnt = 0.f;
    #pragma unroll
    for (int i = 0; i < 16; ++i) {
        vals[i] = __expf(vals[i] - smax);
        sume += vals[i];
        cnt  += msk[i] ? 0.f : 1.f;
    }
    sume += __shfl_xor(sume, 1);  cnt += __shfl_xor(cnt, 1);
    sume += __shfl_xor(sume, 2);  cnt += __shfl_xor(cnt, 2);
    sume += __shfl_xor(sume, 4);  cnt += __shfl_xor(cnt, 4);
    const float invse = 1.f / sume;
    const float invd  = 1.f / cnt;
    f16x8 wv0, wv1;
    #pragma unroll
    for (int i = 0; i < 8; ++i) {
        wv0[i] = (_Float16)(vals[i]     * invse);
        wv1[i] = (_Float16)(vals[i + 8] * invse);
    }
    *(f16x8*)&wLDS[r * WPAD + sl*16]     = wv0;
    *(f16x8*)&wLDS[r * WPAD + sl*16 + 8] = wv1;
    // mean: 64 e per thread, coalesced 256B/row-group
    const float* mrow = msum + (size_t)bq * DD;
    #pragma unroll
    for (int i = 0; i < 8; ++i) {
        int e = i*64 + sl*8;
        f32x4 m0 = *(const f32x4*)(mrow + e);
        f32x4 m1 = *(const f32x4*)(mrow + e + 4);
        f16x8 mh;
        #pragma unroll
        for (int c = 0; c < 4; ++c) {
            mh[c]     = (_Float16)(m0[c] * invd);
            mh[c + 4] = (_Float16)(m1[c] * invd);
        }
        *(f16x8*)&meanLDS[r * MPAD + e] = mh;
    }
    __syncthreads();

    // ---- phase B: gate GEMM (K=512, 4 chunks of 128) ----
    f32x4 accg = (f32x4){0.f, 0.f, 0.f, 0.f};
    const int a_off = (wm*16 + lr) * MPAD + quad*8;
    const int b_off = (wn*16 + lr) * WPAD + quad*8;
    const int st_off = r * WPAD + sl*16;
    #pragma unroll
    for (int cc = 0; cc < 4; ++cc) {
        const _Float16* wrow = WseT + (size_t)(d0 + r) * DD + cc*128 + sl*16;
        f16x8 bw0 = *(const f16x8*)(wrow);
        f16x8 bw1 = *(const f16x8*)(wrow + 8);
        *(f16x8*)&BLDS[st_off]     = bw0;
        *(f16x8*)&BLDS[st_off + 8] = bw1;
        __syncthreads();
        #pragma unroll
        for (int ks = 0; ks < 4; ++ks) {
            f16x8 fa = *(const f16x8*)&meanLDS[a_off + cc*128 + ks*32];
            f16x8 fb = *(const f16x8*)&BLDS[b_off + ks*32];
            accg = __builtin_amdgcn_mfma_f32_16x16x32_f16(fa, fb, accg, 0, 0, 0);
        }
        __syncthreads();
    }

    // ---- phase C: out GEMM (K=128) ----
    {
        const _Float16* vrow = vsT + ((size_t)b * DD + d0 + r) * VAL + sl*16;
        f16x8 bv0 = *(const f16x8*)(vrow);
        f16x8 bv1 = *(const f16x8*)(vrow + 8);
        *(f16x8*)&BLDS[st_off]     = bv0;
        *(f16x8*)&BLDS[st_off + 8] = bv1;
    }
    __syncthreads();
    f32x4 acco = (f32x4){0.f, 0.f, 0.f, 0.f};
    const int w_off = (wm*16 + lr) * WPAD + quad*8;
    #pragma unroll
    for (int ks = 0; ks < 4; ++ks) {
        f16x8 fa = *(const f16x8*)&wLDS[w_off + ks*32];
        f16x8 fb = *(const f16x8*)&BLDS[b_off + ks*32];
        acco = __builtin_amdgcn_mfma_f32_16x16x32_f16(fa, fb, acco, 0, 0, 0);
    }

    // ---- phase D: epilogue. C/D: col=lr (d), row=quad*4+reg (q) ----
    const int d = d0 + wn*16 + lr;
    const float bsev = bse[d];
    #pragma unroll
    for (int reg = 0; reg < 4; ++reg) {
        int q = q0 + wm*16 + quad*4 + reg;
        float g = fmaxf(accg[reg] + bsev, 0.f);
        g = 1.f / (1.f + __expf(-g));
        out[(size_t)q * DD + d] = g * acco[reg];
    }
}

extern "C" void kernel_launch(void* const* d_in, const int* in_sizes, int n_in,
                              void* d_out, int out_size, void* d_ws, size_t ws_size,
                              hipStream_t stream) {
    (void)in_sizes; (void)n_in; (void)out_size; (void)ws_size;
    const float* qs1 = (const float*)d_in[0];
    const float* ks  = (const float*)d_in[2];
    const float* vs  = (const float*)d_in[3];
    const int*   sg  = (const int*)d_in[4];
    const float* W1  = (const float*)d_in[5];
    const float* b1  = (const float*)d_in[6];
    const float* Wse = (const float*)d_in[7];
    const float* bse = (const float*)d_in[8];
    const float* W2  = (const float*)d_in[9];
    const float* b2  = (const float*)d_in[10];
    float* out = (float*)d_out;

    char* ws = (char*)d_ws;
    _Float16* W1T    = (_Float16*)(ws);                        // 512 KB
    _Float16* WseT   = (_Float16*)(ws + (512 << 10));          // 512 KB
    _Float16* vsT    = (_Float16*)(ws + (1 << 20));            // 512 KB
    float*    s_part = (float*)(ws + (1536 << 10));            // 512 KB
    float*    msum   = (float*)(ws + (2 << 20));               // 1 MB

    prep_kernel<<<dim3(16, 36), 256, 0, stream>>>(W1, W1T, Wse, WseT, vs, vsT);
    gemm_h_kernel<<<dim3(BQ, 2), 512, 0, stream>>>(qs1, ks, sg, W1T, b1, W2, s_part, msum);
    final_kernel<<<dim3(16, 16), 256, 0, stream>>>(s_part, msum, sg, WseT, vsT, bse, b2, out);
}

// Round 10
// 126.437 us; speedup vs baseline: 2.1481x; 1.0435x over previous
//
#include <hip/hip_runtime.h>
#include <stdint.h>
#include <stddef.h>

#define BDIM 4
#define QUE  128
#define VAL  128
#define DD   512
#define BQ   (BDIM*QUE)
#define BK   64
// gemm LDS: 8 slots of 8 f16 (16B) per row; true kseg c stored at slot (c + (r&7)) & 7

typedef float    f32x4 __attribute__((ext_vector_type(4)));
typedef float    f32x2 __attribute__((ext_vector_type(2)));
typedef _Float16 f16x8 __attribute__((ext_vector_type(8)));
typedef _Float16 f16x4 __attribute__((ext_vector_type(4)));
typedef _Float16 f16x2 __attribute__((ext_vector_type(2)));

typedef const __attribute__((address_space(1))) void* gas_ptr;
typedef __attribute__((address_space(3))) void*       las_ptr;

__device__ __forceinline__ void async_copy16(const void* g, void* l) {
    __builtin_amdgcn_global_load_lds((gas_ptr)g, (las_ptr)l, 16, 0, 0);
}

// ---------------- prep: fp16 transposes  W1->W1T[e][d], Wse->WseT[d][e],
//                  vs->vsT[b][d][v]; flat fp16 casts qs1->qH, ks->ksH ----------
__global__ __launch_bounds__(256) void prep_kernel(const float* __restrict__ W1,
                                                   _Float16* __restrict__ W1T,
                                                   const float* __restrict__ Wse,
                                                   _Float16* __restrict__ WseT,
                                                   const float* __restrict__ vs,
                                                   _Float16* __restrict__ vsT,
                                                   const float* __restrict__ qs1,
                                                   _Float16* __restrict__ qH,
                                                   const float* __restrict__ ks,
                                                   _Float16* __restrict__ ksH) {
    const int gx = blockIdx.x, gy = blockIdx.y;
    if (gy >= 36) {
        // flat cast: gy==36 -> qs1->qH, gy==37 -> ks->ksH (262144 f32 each)
        const float* src = (gy == 36) ? qs1 : ks;
        _Float16*    dst = (gy == 36) ? qH  : ksH;
        size_t base = (size_t)gx * 16384 + threadIdx.x * 4;
        #pragma unroll 4
        for (int i = 0; i < 16; ++i) {
            f32x4 w = *(const f32x4*)(src + base + (size_t)i * 1024);
            f16x4 h;
            h[0] = (_Float16)w[0]; h[1] = (_Float16)w[1];
            h[2] = (_Float16)w[2]; h[3] = (_Float16)w[3];
            *(f16x4*)(dst + base + (size_t)i * 1024) = h;
        }
        return;
    }
    __shared__ float tile[32][33];
    const int tx = threadIdx.x & 31;
    const int ty = threadIdx.x >> 5;      // 0..7
    if (gy < 32) {
        const float* src = (gy < 16) ? W1  : Wse;
        _Float16*    dst = (gy < 16) ? W1T : WseT;
        int a0 = gx * 32;                 // source-row tile
        int b0 = (gy & 15) * 32;          // source-col tile
        #pragma unroll
        for (int r = 0; r < 4; ++r)
            tile[ty + r*8][tx] = src[(size_t)(a0 + ty + r*8) * DD + b0 + tx];
        __syncthreads();
        #pragma unroll
        for (int r = 0; r < 4; ++r) {
            int el = ty + r*8;
            dst[(size_t)(b0 + el) * DD + a0 + tx] = (_Float16)tile[tx][el];
        }
    } else {
        // vs[b][v][d] -> vsT[b][d][v], b = gy-32, d-tile = gx
        int bb = gy - 32;
        const float* src = vs  + (size_t)bb * VAL * DD;
        _Float16*    dst = vsT + (size_t)bb * DD * VAL;
        int b0 = gx * 32;                 // d tile
        for (int vt = 0; vt < 4; ++vt) {
            int a0 = vt * 32;             // v tile
            __syncthreads();
            #pragma unroll
            for (int r = 0; r < 4; ++r)
                tile[ty + r*8][tx] = src[(size_t)(a0 + ty + r*8) * DD + b0 + tx];
            __syncthreads();
            #pragma unroll
            for (int r = 0; r < 4; ++r) {
                int el = ty + r*8;
                dst[(size_t)(b0 + el) * VAL + a0 + tx] = (_Float16)tile[tx][el];
            }
        }
    }
}

// ---------------- fused GEMM: h=relu((q*k)@W1+b1); emit s-partials + masked colsums
// grid (BQ, 2); block 512 = 8 waves as 2m x 4n of 64x64. Tile 128 rows x 256 e-cols.
// BK=64 (r8 winner); A built from fp16 qH/ksH with packed v_pk_mul_f16.
__global__ __launch_bounds__(512, 4) void gemm_h_kernel(
    const _Float16* __restrict__ qH,    // [BQ][DD] fp16
    const _Float16* __restrict__ ksH,   // [B][VAL][DD] fp16
    const int*   __restrict__ sgmask,
    const _Float16* __restrict__ W1T,   // [e][d] fp16
    const float* __restrict__ b1,
    const float* __restrict__ W2,
    float* __restrict__ s_part,         // [BQ][2][VAL]
    float* __restrict__ meansum)        // [BQ][DD]
{
    __shared__ _Float16 Ah[128 * BK];     // x tile   [v][k]  16 KB
    __shared__ _Float16 Bh[256 * BK];     // W1T tile [e][k]  32 KB
    __shared__ _Float16 qrowH[DD];
    __shared__ float sred[4][VAL];
    __shared__ float msumLDS[2][256];

    const int tid  = threadIdx.x;
    const int bq   = blockIdx.x;
    const int gy   = blockIdx.y;          // e-half: cols [gy*256, gy*256+256)
    const int b    = bq >> 7;
    const int lane = tid & 63;
    const int wid  = tid >> 6;            // 0..7
    const int wm   = wid >> 2;            // 0..1 (rows wm*64)
    const int wn   = wid & 3;             // 0..3 (cols wn*64)
    const int quad = lane >> 4;
    const int lr   = lane & 15;

    if (tid < 64)
        *(f16x8*)(qrowH + tid * 8) = *(const f16x8*)(qH + (size_t)bq * DD + tid * 8);

    f32x4 acc[4][4];
    #pragma unroll
    for (int i = 0; i < 4; ++i)
        #pragma unroll
        for (int j = 0; j < 4; ++j) acc[i][j] = (f32x4){0.f, 0.f, 0.f, 0.f};

    // ---- A staging: 2 chunks/thread (chunk = tid, tid+512); chunk -> row=c>>3, slot=c&7
    const int ar0 = tid >> 3;             // chunk tid   -> row 0..63
    const int ar1 = 64 + ar0;             // chunk tid+512 -> row 64..127
    const int slt = tid & 7;
    const int ca0 = (slt - (ar0 & 7)) & 7;   // true kseg
    const int ca1 = (slt - (ar1 & 7)) & 7;
    const _Float16* ksrow0 = ksH + ((size_t)b * VAL + ar0) * DD + ca0 * 8;
    const _Float16* ksrow1 = ksH + ((size_t)b * VAL + ar1) * DD + ca1 * 8;
    const _Float16* qb0 = qrowH + ca0 * 8;
    const _Float16* qb1 = qrowH + ca1 * 8;
    const int aoff0 = tid * 8;            // chunk*8 f16 == row*BK + slot*8
    const int aoff1 = (512 + tid) * 8;

    // ---- B staging: 4 asyncs/thread; async j covers chunks j*512 + tid ----
    const _Float16* gB[4];
    int ldsBoff[4];                       // f16 units, wave-uniform + lane*16B implicit
    #pragma unroll
    for (int j = 0; j < 4; ++j) {
        int chunk = j * 512 + tid;
        int row   = chunk >> 3;           // 0..255
        int c     = ((chunk & 7) - (row & 7)) & 7;
        gB[j] = W1T + (size_t)(gy * 256 + row) * DD + c * 8;
        ldsBoff[j] = (j * 512 + wid * 64) * 8;   // wave-uniform chunk base * 8 f16
    }

    // ---- fragment offsets (f16 units); sub-step 1 = offset XOR 32 (slot+4 mod 8) ----
    int faoff[4], fboff[4];
    #pragma unroll
    for (int mt = 0; mt < 4; ++mt) {
        int row = wm * 64 + mt * 16 + lr;
        faoff[mt] = row * BK + (((quad + row) & 7) << 3);
    }
    #pragma unroll
    for (int nt = 0; nt < 4; ++nt) {
        int row = wn * 64 + nt * 16 + lr;
        fboff[nt] = row * BK + (((quad + row) & 7) << 3);
    }
    __syncthreads();   // qrowH ready

    for (int kk = 0; kk < DD; kk += BK) {
        #pragma unroll
        for (int j = 0; j < 4; ++j)
            async_copy16(gB[j] + kk, &Bh[ldsBoff[j]]);
        {
            f16x8 kv = *(const f16x8*)(ksrow0 + kk);
            f16x8 qv = *(const f16x8*)(qb0 + kk);
            *(f16x8*)&Ah[aoff0] = kv * qv;     // v_pk_mul_f16 x4
        }
        {
            f16x8 kv = *(const f16x8*)(ksrow1 + kk);
            f16x8 qv = *(const f16x8*)(qb1 + kk);
            *(f16x8*)&Ah[aoff1] = kv * qv;
        }
        __syncthreads();

        #pragma unroll
        for (int sub = 0; sub < 2; ++sub) {
            const int sx = sub << 5;      // 0 or 32 f16
            f16x8 fa[4];
            #pragma unroll
            for (int mt = 0; mt < 4; ++mt)
                fa[mt] = *(const f16x8*)&Ah[faoff[mt] ^ sx];
            #pragma unroll
            for (int nt = 0; nt < 4; ++nt) {
                f16x8 fb = *(const f16x8*)&Bh[fboff[nt] ^ sx];
                #pragma unroll
                for (int mt = 0; mt < 4; ++mt)
                    acc[mt][nt] = __builtin_amdgcn_mfma_f32_16x16x32_f16(fa[mt], fb, acc[mt][nt], 0, 0, 0);
            }
        }
        __syncthreads();
    }

    // ---- fused epilogue: C/D layout col=lr (e), row=quad*4+reg (v)
    float b1v[4], w2v[4];
    #pragma unroll
    for (int nt = 0; nt < 4; ++nt) {
        int col = gy*256 + wn*64 + nt*16 + lr;
        b1v[nt] = b1[col];
        w2v[nt] = W2[col];
    }
    float msum[4] = {0.f, 0.f, 0.f, 0.f};
    #pragma unroll
    for (int mt = 0; mt < 4; ++mt) {
        #pragma unroll
        for (int reg = 0; reg < 4; ++reg) {
            int v = wm*64 + mt*16 + quad*4 + reg;
            int masked = sgmask[b * VAL + v];
            float sacc = 0.f;
            #pragma unroll
            for (int nt = 0; nt < 4; ++nt) {
                float h = acc[mt][nt][reg] + b1v[nt];
                h = fmaxf(h, 0.f);
                sacc += h * w2v[nt];
                if (!masked) msum[nt] += h;
            }
            sacc += __shfl_xor(sacc, 1);
            sacc += __shfl_xor(sacc, 2);
            sacc += __shfl_xor(sacc, 4);
            sacc += __shfl_xor(sacc, 8);
            if (lr == 0) sred[wn][v] = sacc;
        }
    }
    #pragma unroll
    for (int nt = 0; nt < 4; ++nt) {
        float m = msum[nt];
        m += __shfl_xor(m, 16);
        m += __shfl_xor(m, 32);
        if (lane < 16) msumLDS[wm][wn*64 + nt*16 + lr] = m;
    }
    __syncthreads();
    if (tid < 128) {
        s_part[((size_t)bq * 2 + gy) * VAL + tid] =
            sred[0][tid] + sred[1][tid] + sred[2][tid] + sred[3][tid];
    } else if (tid >= 256) {
        int c = tid - 256;
        meansum[(size_t)bq * DD + gy*256 + c] = msumLDS[0][c] + msumLDS[1][c];
    }
}

// ---------------- final (fuses mid): softmax+mean in-block, then two LDS-staged
// mini-GEMMs. grid (16 q-tiles of 32, 16 d-tiles of 32), 256 thr = 4 waves (2m x 2n).
#define MPAD 514   // meanLDS row stride (f16): 257 dwords === 1 mod 32 -> conflict-free
#define WPAD 130   // wLDS/BLDS row stride: 65 dwords === 1 mod 32
__global__ __launch_bounds__(256) void final_kernel(
    const float* __restrict__ s_part,     // [BQ][2][VAL]
    const float* __restrict__ msum,       // [BQ][DD]
    const int*   __restrict__ sgmask,
    const _Float16* __restrict__ WseT,    // [d][e] fp16
    const _Float16* __restrict__ vsT,     // [b][d][v] fp16
    const float* __restrict__ bse,
    const float* __restrict__ b2,
    float* __restrict__ out)              // [BQ][DD]
{
    __shared__ _Float16 meanLDS[32 * MPAD];   // 32.9 KB  A of gate GEMM (all 512 e)
    __shared__ _Float16 wLDS[32 * WPAD];      //  8.3 KB  A of out GEMM
    __shared__ _Float16 BLDS[32 * WPAD];      //  8.3 KB  B chunk (WseT then vsT)

    const int tid  = threadIdx.x;
    const int q0   = blockIdx.x * 32;
    const int d0   = blockIdx.y * 32;
    const int b    = q0 >> 7;                 // whole q-tile within one batch
    const int lane = tid & 63;
    const int wid  = tid >> 6;                // 0..3
    const int wm   = wid >> 1, wn = wid & 1;  // 2m x 2n of 16x16
    const int quad = lane >> 4;
    const int lr   = lane & 15;
    const int r    = tid >> 3;                // 0..31 (row for staging/softmax)
    const int sl   = tid & 7;                 // 0..7  (segment)

    // ---- phase A: softmax over v (8 lanes/row) + mean (fold 1/denom) ----
    const float b2v = b2[0];
    const int   bq  = q0 + r;
    const float* sp = s_part + (size_t)bq * 2 * VAL;
    float vals[16];
    int   msk[16];
    float smax = -3.4e38f;
    #pragma unroll
    for (int i4 = 0; i4 < 4; ++i4) {
        f32x4 s0 = *(const f32x4*)(sp + sl*16 + i4*4);
        f32x4 s1 = *(const f32x4*)(sp + VAL + sl*16 + i4*4);
        #pragma unroll
        for (int j = 0; j < 4; ++j) {
            int idx = i4*4 + j;
            int v   = sl*16 + idx;
            float s = fmaxf(s0[j] + s1[j] + b2v, 0.f);
            int m   = sgmask[b * VAL + v];
            msk[idx] = m;
            if (m) s = -1e9f;
            vals[idx] = s;
            smax = fmaxf(smax, s);
        }
    }
    smax = fmaxf(smax, __shfl_xor(smax, 1));
    smax = fmaxf(smax, __shfl_xor(smax, 2));
    smax = fmaxf(smax, __shfl_xor(smax, 4));
    float sume = 0.f, cnt = 0.f;
    #pragma unroll
    for (int i = 0; i < 16; ++i) {
        vals[i] = __expf(vals[i] - smax);
        sume += vals[i];
        cnt  += msk[i] ? 0.f : 1.f;
    }
    sume += __shfl_xor(sume, 1);  cnt += __shfl_xor(cnt, 1);
    sume += __shfl_xor(sume, 2);  cnt += __shfl_xor(cnt, 2);
    sume += __shfl_xor(sume, 4);  cnt += __shfl_xor(cnt, 4);
    const float invse = 1.f / sume;
    const float invd  = 1.f / cnt;
    f16x8 wv0, wv1;
    #pragma unroll
    for (int i = 0; i < 8; ++i) {
        wv0[i] = (_Float16)(vals[i]     * invse);
        wv1[i] = (_Float16)(vals[i + 8] * invse);
    }
    *(f16x8*)&wLDS[r * WPAD + sl*16]     = wv0;
    *(f16x8*)&wLDS[r * WPAD + sl*16 + 8] = wv1;
    // mean: 64 e per thread, coalesced 256B/row-group
    const float* mrow = msum + (size_t)bq * DD;
    #pragma unroll
    for (int i = 0; i < 8; ++i) {
        int e = i*64 + sl*8;
        f32x4 m0 = *(const f32x4*)(mrow + e);
        f32x4 m1 = *(const f32x4*)(mrow + e + 4);
        f16x8 mh;
        #pragma unroll
        for (int c = 0; c < 4; ++c) {
            mh[c]     = (_Float16)(m0[c] * invd);
            mh[c + 4] = (_Float16)(m1[c] * invd);
        }
        *(f16x8*)&meanLDS[r * MPAD + e] = mh;
    }
    __syncthreads();

    // ---- phase B: gate GEMM (K=512, 4 chunks of 128) ----
    f32x4 accg = (f32x4){0.f, 0.f, 0.f, 0.f};
    const int a_off = (wm*16 + lr) * MPAD + quad*8;
    const int b_off = (wn*16 + lr) * WPAD + quad*8;
    const int st_off = r * WPAD + sl*16;
    #pragma unroll
    for (int cc = 0; cc < 4; ++cc) {
        const _Float16* wrow = WseT + (size_t)(d0 + r) * DD + cc*128 + sl*16;
        f16x8 bw0 = *(const f16x8*)(wrow);
        f16x8 bw1 = *(const f16x8*)(wrow + 8);
        *(f16x8*)&BLDS[st_off]     = bw0;
        *(f16x8*)&BLDS[st_off + 8] = bw1;
        __syncthreads();
        #pragma unroll
        for (int ks = 0; ks < 4; ++ks) {
            f16x8 fa = *(const f16x8*)&meanLDS[a_off + cc*128 + ks*32];
            f16x8 fb = *(const f16x8*)&BLDS[b_off + ks*32];
            accg = __builtin_amdgcn_mfma_f32_16x16x32_f16(fa, fb, accg, 0, 0, 0);
        }
        __syncthreads();
    }

    // ---- phase C: out GEMM (K=128) ----
    {
        const _Float16* vrow = vsT + ((size_t)b * DD + d0 + r) * VAL + sl*16;
        f16x8 bv0 = *(const f16x8*)(vrow);
        f16x8 bv1 = *(const f16x8*)(vrow + 8);
        *(f16x8*)&BLDS[st_off]     = bv0;
        *(f16x8*)&BLDS[st_off + 8] = bv1;
    }
    __syncthreads();
    f32x4 acco = (f32x4){0.f, 0.f, 0.f, 0.f};
    const int w_off = (wm*16 + lr) * WPAD + quad*8;
    #pragma unroll
    for (int ks = 0; ks < 4; ++ks) {
        f16x8 fa = *(const f16x8*)&wLDS[w_off + ks*32];
        f16x8 fb = *(const f16x8*)&BLDS[b_off + ks*32];
        acco = __builtin_amdgcn_mfma_f32_16x16x32_f16(fa, fb, acco, 0, 0, 0);
    }

    // ---- phase D: epilogue. C/D: col=lr (d), row=quad*4+reg (q) ----
    const int d = d0 + wn*16 + lr;
    const float bsev = bse[d];
    #pragma unroll
    for (int reg = 0; reg < 4; ++reg) {
        int q = q0 + wm*16 + quad*4 + reg;
        float g = fmaxf(accg[reg] + bsev, 0.f);
        g = 1.f / (1.f + __expf(-g));
        out[(size_t)q * DD + d] = g * acco[reg];
    }
}

extern "C" void kernel_launch(void* const* d_in, const int* in_sizes, int n_in,
                              void* d_out, int out_size, void* d_ws, size_t ws_size,
                              hipStream_t stream) {
    (void)in_sizes; (void)n_in; (void)out_size; (void)ws_size;
    const float* qs1 = (const float*)d_in[0];
    const float* ks  = (const float*)d_in[2];
    const float* vs  = (const float*)d_in[3];
    const int*   sg  = (const int*)d_in[4];
    const float* W1  = (const float*)d_in[5];
    const float* b1  = (const float*)d_in[6];
    const float* Wse = (const float*)d_in[7];
    const float* bse = (const float*)d_in[8];
    const float* W2  = (const float*)d_in[9];
    const float* b2  = (const float*)d_in[10];
    float* out = (float*)d_out;

    char* ws = (char*)d_ws;
    _Float16* W1T    = (_Float16*)(ws);                        // 512 KB
    _Float16* WseT   = (_Float16*)(ws + (512 << 10));          // 512 KB
    _Float16* vsT    = (_Float16*)(ws + (1 << 20));            // 512 KB
    float*    s_part = (float*)(ws + (1536 << 10));            // 512 KB
    float*    msum   = (float*)(ws + (2 << 20));               // 1 MB
    _Float16* qH     = (_Float16*)(ws + (3 << 20));            // 512 KB
    _Float16* ksH    = (_Float16*)(ws + (3 << 20) + (512 << 10)); // 512 KB

    prep_kernel<<<dim3(16, 38), 256, 0, stream>>>(W1, W1T, Wse, WseT, vs, vsT,
                                                  qs1, qH, ks, ksH);
    gemm_h_kernel<<<dim3(BQ, 2), 512, 0, stream>>>(qH, ksH, sg, W1T, b1, W2, s_part, msum);
    final_kernel<<<dim3(16, 16), 256, 0, stream>>>(s_part, msum, sg, WseT, vsT, bse, b2, out);
}

// Round 11
// 126.401 us; speedup vs baseline: 2.1487x; 1.0003x over previous
//
#include <hip/hip_runtime.h>
#include <stdint.h>
#include <stddef.h>

#define BDIM 4
#define QUE  128
#define VAL  128
#define DD   512
#define BQ   (BDIM*QUE)
#define BK   64
// gemm LDS: 8 slots of 8 f16 (16B) per row; true kseg c stored at slot (c + (r&7)) & 7

typedef float    f32x4 __attribute__((ext_vector_type(4)));
typedef float    f32x2 __attribute__((ext_vector_type(2)));
typedef _Float16 f16x8 __attribute__((ext_vector_type(8)));
typedef _Float16 f16x4 __attribute__((ext_vector_type(4)));
typedef _Float16 f16x2 __attribute__((ext_vector_type(2)));

typedef const __attribute__((address_space(1))) void* gas_ptr;
typedef __attribute__((address_space(3))) void*       las_ptr;

__device__ __forceinline__ void async_copy16(const void* g, void* l) {
    __builtin_amdgcn_global_load_lds((gas_ptr)g, (las_ptr)l, 16, 0, 0);
}

// ---------------- prep: fp16 transposes  W1->W1T[e][d], Wse->WseT[d][e],
//                  vs->vsT[b][d][v]; flat fp16 casts qs1->qH, ks->ksH ----------
__global__ __launch_bounds__(256) void prep_kernel(const float* __restrict__ W1,
                                                   _Float16* __restrict__ W1T,
                                                   const float* __restrict__ Wse,
                                                   _Float16* __restrict__ WseT,
                                                   const float* __restrict__ vs,
                                                   _Float16* __restrict__ vsT,
                                                   const float* __restrict__ qs1,
                                                   _Float16* __restrict__ qH,
                                                   const float* __restrict__ ks,
                                                   _Float16* __restrict__ ksH) {
    const int gx = blockIdx.x, gy = blockIdx.y;
    if (gy >= 36) {
        // flat cast: gy==36 -> qs1->qH, gy==37 -> ks->ksH (262144 f32 each)
        const float* src = (gy == 36) ? qs1 : ks;
        _Float16*    dst = (gy == 36) ? qH  : ksH;
        size_t base = (size_t)gx * 16384 + threadIdx.x * 4;
        #pragma unroll 4
        for (int i = 0; i < 16; ++i) {
            f32x4 w = *(const f32x4*)(src + base + (size_t)i * 1024);
            f16x4 h;
            h[0] = (_Float16)w[0]; h[1] = (_Float16)w[1];
            h[2] = (_Float16)w[2]; h[3] = (_Float16)w[3];
            *(f16x4*)(dst + base + (size_t)i * 1024) = h;
        }
        return;
    }
    __shared__ float tile[32][33];
    const int tx = threadIdx.x & 31;
    const int ty = threadIdx.x >> 5;      // 0..7
    if (gy < 32) {
        const float* src = (gy < 16) ? W1  : Wse;
        _Float16*    dst = (gy < 16) ? W1T : WseT;
        int a0 = gx * 32;                 // source-row tile
        int b0 = (gy & 15) * 32;          // source-col tile
        #pragma unroll
        for (int r = 0; r < 4; ++r)
            tile[ty + r*8][tx] = src[(size_t)(a0 + ty + r*8) * DD + b0 + tx];
        __syncthreads();
        #pragma unroll
        for (int r = 0; r < 4; ++r) {
            int el = ty + r*8;
            dst[(size_t)(b0 + el) * DD + a0 + tx] = (_Float16)tile[tx][el];
        }
    } else {
        // vs[b][v][d] -> vsT[b][d][v], b = gy-32, d-tile = gx
        int bb = gy - 32;
        const float* src = vs  + (size_t)bb * VAL * DD;
        _Float16*    dst = vsT + (size_t)bb * DD * VAL;
        int b0 = gx * 32;                 // d tile
        for (int vt = 0; vt < 4; ++vt) {
            int a0 = vt * 32;             // v tile
            __syncthreads();
            #pragma unroll
            for (int r = 0; r < 4; ++r)
                tile[ty + r*8][tx] = src[(size_t)(a0 + ty + r*8) * DD + b0 + tx];
            __syncthreads();
            #pragma unroll
            for (int r = 0; r < 4; ++r) {
                int el = ty + r*8;
                dst[(size_t)(b0 + el) * VAL + a0 + tx] = (_Float16)tile[tx][el];
            }
        }
    }
}

// ---------------- fused GEMM: h=relu((q*k)@W1+b1); emit s-partials + masked colsums
// grid (BQ, 2); block 512 = 8 waves as 2m x 4n of 64x64. Tile 128 rows x 256 e-cols.
// BK=64; A inputs REGISTER-PREFETCHED one K-step ahead (land under MFMA phase);
// q read direct from global (L1-broadcast) — no qrowH LDS, no pre-loop barrier.
__global__ __launch_bounds__(512, 4) void gemm_h_kernel(
    const _Float16* __restrict__ qH,    // [BQ][DD] fp16
    const _Float16* __restrict__ ksH,   // [B][VAL][DD] fp16
    const int*   __restrict__ sgmask,
    const _Float16* __restrict__ W1T,   // [e][d] fp16
    const float* __restrict__ b1,
    const float* __restrict__ W2,
    float* __restrict__ s_part,         // [BQ][2][VAL]
    float* __restrict__ meansum)        // [BQ][DD]
{
    __shared__ _Float16 Ah[128 * BK];     // x tile   [v][k]  16 KB
    __shared__ _Float16 Bh[256 * BK];     // W1T tile [e][k]  32 KB
    __shared__ float sred[4][VAL];
    __shared__ float msumLDS[2][256];

    const int tid  = threadIdx.x;
    const int bq   = blockIdx.x;
    const int gy   = blockIdx.y;          // e-half: cols [gy*256, gy*256+256)
    const int b    = bq >> 7;
    const int lane = tid & 63;
    const int wid  = tid >> 6;            // 0..7
    const int wm   = wid >> 2;            // 0..1 (rows wm*64)
    const int wn   = wid & 3;             // 0..3 (cols wn*64)
    const int quad = lane >> 4;
    const int lr   = lane & 15;

    f32x4 acc[4][4];
    #pragma unroll
    for (int i = 0; i < 4; ++i)
        #pragma unroll
        for (int j = 0; j < 4; ++j) acc[i][j] = (f32x4){0.f, 0.f, 0.f, 0.f};

    // ---- A staging: 2 chunks/thread (chunk = tid, tid+512); chunk -> row=c>>3, slot=c&7
    const int ar0 = tid >> 3;             // chunk tid   -> row 0..63
    const int slt = tid & 7;
    const int ca0 = (slt - (ar0 & 7)) & 7;   // true kseg; rows ar0 and ar0+64 share it
    const _Float16* ksrow0 = ksH + ((size_t)b * VAL + ar0)      * DD + ca0 * 8;
    const _Float16* ksrow1 = ksH + ((size_t)b * VAL + 64 + ar0) * DD + ca0 * 8;
    const _Float16* qrow_g = qH  + (size_t)bq * DD + ca0 * 8;   // L1-broadcast row
    const int aoff0 = tid * 8;            // chunk*8 f16 == row*BK + slot*8
    const int aoff1 = (512 + tid) * 8;

    // ---- B staging: 4 asyncs/thread; async j covers chunks j*512 + tid ----
    const _Float16* gB[4];
    int ldsBoff[4];                       // f16 units, wave-uniform + lane*16B implicit
    #pragma unroll
    for (int j = 0; j < 4; ++j) {
        int chunk = j * 512 + tid;
        int row   = chunk >> 3;           // 0..255
        int c     = ((chunk & 7) - (row & 7)) & 7;
        gB[j] = W1T + (size_t)(gy * 256 + row) * DD + c * 8;
        ldsBoff[j] = (j * 512 + wid * 64) * 8;   // wave-uniform chunk base * 8 f16
    }

    // ---- fragment offsets (f16 units); sub-step 1 = offset XOR 32 (slot+4 mod 8) ----
    int faoff[4], fboff[4];
    #pragma unroll
    for (int mt = 0; mt < 4; ++mt) {
        int row = wm * 64 + mt * 16 + lr;
        faoff[mt] = row * BK + (((quad + row) & 7) << 3);
    }
    #pragma unroll
    for (int nt = 0; nt < 4; ++nt) {
        int row = wn * 64 + nt * 16 + lr;
        fboff[nt] = row * BK + (((quad + row) & 7) << 3);
    }

    // ---- prologue: prefetch A-inputs for step 0 ----
    f16x8 kv0 = *(const f16x8*)(ksrow0);
    f16x8 kv1 = *(const f16x8*)(ksrow1);
    f16x8 qv  = *(const f16x8*)(qrow_g);

    for (int i = 0; i < 8; ++i) {
        const int kk = i * BK;
        // ---- B: 4 async global->LDS for this step
        #pragma unroll
        for (int j = 0; j < 4; ++j)
            async_copy16(gB[j] + kk, &Bh[ldsBoff[j]]);
        // ---- A: stage from prefetched registers (pure VALU + ds_write)
        *(f16x8*)&Ah[aoff0] = kv0 * qv;   // v_pk_mul_f16 x4
        *(f16x8*)&Ah[aoff1] = kv1 * qv;
        __syncthreads();                  // barrier1: staging visible (vmcnt drain)

        // ---- prefetch A-inputs for step i+1; lands under the MFMA phase
        if (i < 7) {
            kv0 = *(const f16x8*)(ksrow0 + kk + BK);
            kv1 = *(const f16x8*)(ksrow1 + kk + BK);
            qv  = *(const f16x8*)(qrow_g + kk + BK);
        }
        // ---- MFMA: two K=32 sub-steps; sub-step toggles slot by XOR 32 f16
        #pragma unroll
        for (int sub = 0; sub < 2; ++sub) {
            const int sx = sub << 5;      // 0 or 32 f16
            f16x8 fa[4];
            #pragma unroll
            for (int mt = 0; mt < 4; ++mt)
                fa[mt] = *(const f16x8*)&Ah[faoff[mt] ^ sx];
            #pragma unroll
            for (int nt = 0; nt < 4; ++nt) {
                f16x8 fb = *(const f16x8*)&Bh[fboff[nt] ^ sx];
                #pragma unroll
                for (int mt = 0; mt < 4; ++mt)
                    acc[mt][nt] = __builtin_amdgcn_mfma_f32_16x16x32_f16(fa[mt], fb, acc[mt][nt], 0, 0, 0);
            }
        }
        __syncthreads();                  // barrier2: frag reads done, LDS reusable
    }

    // ---- fused epilogue: C/D layout col=lr (e), row=quad*4+reg (v)
    float b1v[4], w2v[4];
    #pragma unroll
    for (int nt = 0; nt < 4; ++nt) {
        int col = gy*256 + wn*64 + nt*16 + lr;
        b1v[nt] = b1[col];
        w2v[nt] = W2[col];
    }
    float msum[4] = {0.f, 0.f, 0.f, 0.f};
    #pragma unroll
    for (int mt = 0; mt < 4; ++mt) {
        #pragma unroll
        for (int reg = 0; reg < 4; ++reg) {
            int v = wm*64 + mt*16 + quad*4 + reg;
            int masked = sgmask[b * VAL + v];
            float sacc = 0.f;
            #pragma unroll
            for (int nt = 0; nt < 4; ++nt) {
                float h = acc[mt][nt][reg] + b1v[nt];
                h = fmaxf(h, 0.f);
                sacc += h * w2v[nt];
                if (!masked) msum[nt] += h;
            }
            sacc += __shfl_xor(sacc, 1);
            sacc += __shfl_xor(sacc, 2);
            sacc += __shfl_xor(sacc, 4);
            sacc += __shfl_xor(sacc, 8);
            if (lr == 0) sred[wn][v] = sacc;
        }
    }
    #pragma unroll
    for (int nt = 0; nt < 4; ++nt) {
        float m = msum[nt];
        m += __shfl_xor(m, 16);
        m += __shfl_xor(m, 32);
        if (lane < 16) msumLDS[wm][wn*64 + nt*16 + lr] = m;
    }
    __syncthreads();
    if (tid < 128) {
        s_part[((size_t)bq * 2 + gy) * VAL + tid] =
            sred[0][tid] + sred[1][tid] + sred[2][tid] + sred[3][tid];
    } else if (tid >= 256) {
        int c = tid - 256;
        meansum[(size_t)bq * DD + gy*256 + c] = msumLDS[0][c] + msumLDS[1][c];
    }
}

// ---------------- final (fuses mid): softmax+mean in-block, then two LDS-staged
// mini-GEMMs. grid (16 q-tiles of 32, 16 d-tiles of 32), 256 thr = 4 waves (2m x 2n).
#define MPAD 514   // meanLDS row stride (f16): 257 dwords === 1 mod 32 -> conflict-free
#define WPAD 130   // wLDS/BLDS row stride: 65 dwords === 1 mod 32
__global__ __launch_bounds__(256) void final_kernel(
    const float* __restrict__ s_part,     // [BQ][2][VAL]
    const float* __restrict__ msum,       // [BQ][DD]
    const int*   __restrict__ sgmask,
    const _Float16* __restrict__ WseT,    // [d][e] fp16
    const _Float16* __restrict__ vsT,     // [b][d][v] fp16
    const float* __restrict__ bse,
    const float* __restrict__ b2,
    float* __restrict__ out)              // [BQ][DD]
{
    __shared__ _Float16 meanLDS[32 * MPAD];   // 32.9 KB  A of gate GEMM (all 512 e)
    __shared__ _Float16 wLDS[32 * WPAD];      //  8.3 KB  A of out GEMM
    __shared__ _Float16 BLDS[32 * WPAD];      //  8.3 KB  B chunk (WseT then vsT)

    const int tid  = threadIdx.x;
    const int q0   = blockIdx.x * 32;
    const int d0   = blockIdx.y * 32;
    const int b    = q0 >> 7;                 // whole q-tile within one batch
    const int lane = tid & 63;
    const int wid  = tid >> 6;                // 0..3
    const int wm   = wid >> 1, wn = wid & 1;  // 2m x 2n of 16x16
    const int quad = lane >> 4;
    const int lr   = lane & 15;
    const int r    = tid >> 3;                // 0..31 (row for staging/softmax)
    const int sl   = tid & 7;                 // 0..7  (segment)

    // ---- phase A: softmax over v (8 lanes/row) + mean (fold 1/denom) ----
    const float b2v = b2[0];
    const int   bq  = q0 + r;
    const float* sp = s_part + (size_t)bq * 2 * VAL;
    float vals[16];
    int   msk[16];
    float smax = -3.4e38f;
    #pragma unroll
    for (int i4 = 0; i4 < 4; ++i4) {
        f32x4 s0 = *(const f32x4*)(sp + sl*16 + i4*4);
        f32x4 s1 = *(const f32x4*)(sp + VAL + sl*16 + i4*4);
        #pragma unroll
        for (int j = 0; j < 4; ++j) {
            int idx = i4*4 + j;
            int v   = sl*16 + idx;
            float s = fmaxf(s0[j] + s1[j] + b2v, 0.f);
            int m   = sgmask[b * VAL + v];
            msk[idx] = m;
            if (m) s = -1e9f;
            vals[idx] = s;
            smax = fmaxf(smax, s);
        }
    }
    smax = fmaxf(smax, __shfl_xor(smax, 1));
    smax = fmaxf(smax, __shfl_xor(smax, 2));
    smax = fmaxf(smax, __shfl_xor(smax, 4));
    float sume = 0.f, cnt = 0.f;
    #pragma unroll
    for (int i = 0; i < 16; ++i) {
        vals[i] = __expf(vals[i] - smax);
        sume += vals[i];
        cnt  += msk[i] ? 0.f : 1.f;
    }
    sume += __shfl_xor(sume, 1);  cnt += __shfl_xor(cnt, 1);
    sume += __shfl_xor(sume, 2);  cnt += __shfl_xor(cnt, 2);
    sume += __shfl_xor(sume, 4);  cnt += __shfl_xor(cnt, 4);
    const float invse = 1.f / sume;
    const float invd  = 1.f / cnt;
    f16x8 wv0, wv1;
    #pragma unroll
    for (int i = 0; i < 8; ++i) {
        wv0[i] = (_Float16)(vals[i]     * invse);
        wv1[i] = (_Float16)(vals[i + 8] * invse);
    }
    *(f16x8*)&wLDS[r * WPAD + sl*16]     = wv0;
    *(f16x8*)&wLDS[r * WPAD + sl*16 + 8] = wv1;
    // mean: 64 e per thread, coalesced 256B/row-group
    const float* mrow = msum + (size_t)bq * DD;
    #pragma unroll
    for (int i = 0; i < 8; ++i) {
        int e = i*64 + sl*8;
        f32x4 m0 = *(const f32x4*)(mrow + e);
        f32x4 m1 = *(const f32x4*)(mrow + e + 4);
        f16x8 mh;
        #pragma unroll
        for (int c = 0; c < 4; ++c) {
            mh[c]     = (_Float16)(m0[c] * invd);
            mh[c + 4] = (_Float16)(m1[c] * invd);
        }
        *(f16x8*)&meanLDS[r * MPAD + e] = mh;
    }
    __syncthreads();

    // ---- phase B: gate GEMM (K=512, 4 chunks of 128) ----
    f32x4 accg = (f32x4){0.f, 0.f, 0.f, 0.f};
    const int a_off = (wm*16 + lr) * MPAD + quad*8;
    const int b_off = (wn*16 + lr) * WPAD + quad*8;
    const int st_off = r * WPAD + sl*16;
    #pragma unroll
    for (int cc = 0; cc < 4; ++cc) {
        const _Float16* wrow = WseT + (size_t)(d0 + r) * DD + cc*128 + sl*16;
        f16x8 bw0 = *(const f16x8*)(wrow);
        f16x8 bw1 = *(const f16x8*)(wrow + 8);
        *(f16x8*)&BLDS[st_off]     = bw0;
        *(f16x8*)&BLDS[st_off + 8] = bw1;
        __syncthreads();
        #pragma unroll
        for (int ks = 0; ks < 4; ++ks) {
            f16x8 fa = *(const f16x8*)&meanLDS[a_off + cc*128 + ks*32];
            f16x8 fb = *(const f16x8*)&BLDS[b_off + ks*32];
            accg = __builtin_amdgcn_mfma_f32_16x16x32_f16(fa, fb, accg, 0, 0, 0);
        }
        __syncthreads();
    }

    // ---- phase C: out GEMM (K=128) ----
    {
        const _Float16* vrow = vsT + ((size_t)b * DD + d0 + r) * VAL + sl*16;
        f16x8 bv0 = *(const f16x8*)(vrow);
        f16x8 bv1 = *(const f16x8*)(vrow + 8);
        *(f16x8*)&BLDS[st_off]     = bv0;
        *(f16x8*)&BLDS[st_off + 8] = bv1;
    }
    __syncthreads();
    f32x4 acco = (f32x4){0.f, 0.f, 0.f, 0.f};
    const int w_off = (wm*16 + lr) * WPAD + quad*8;
    #pragma unroll
    for (int ks = 0; ks < 4; ++ks) {
        f16x8 fa = *(const f16x8*)&wLDS[w_off + ks*32];
        f16x8 fb = *(const f16x8*)&BLDS[b_off + ks*32];
        acco = __builtin_amdgcn_mfma_f32_16x16x32_f16(fa, fb, acco, 0, 0, 0);
    }

    // ---- phase D: epilogue. C/D: col=lr (d), row=quad*4+reg (q) ----
    const int d = d0 + wn*16 + lr;
    const float bsev = bse[d];
    #pragma unroll
    for (int reg = 0; reg < 4; ++reg) {
        int q = q0 + wm*16 + quad*4 + reg;
        float g = fmaxf(accg[reg] + bsev, 0.f);
        g = 1.f / (1.f + __expf(-g));
        out[(size_t)q * DD + d] = g * acco[reg];
    }
}

extern "C" void kernel_launch(void* const* d_in, const int* in_sizes, int n_in,
                              void* d_out, int out_size, void* d_ws, size_t ws_size,
                              hipStream_t stream) {
    (void)in_sizes; (void)n_in; (void)out_size; (void)ws_size;
    const float* qs1 = (const float*)d_in[0];
    const float* ks  = (const float*)d_in[2];
    const float* vs  = (const float*)d_in[3];
    const int*   sg  = (const int*)d_in[4];
    const float* W1  = (const float*)d_in[5];
    const float* b1  = (const float*)d_in[6];
    const float* Wse = (const float*)d_in[7];
    const float* bse = (const float*)d_in[8];
    const float* W2  = (const float*)d_in[9];
    const float* b2  = (const float*)d_in[10];
    float* out = (float*)d_out;

    char* ws = (char*)d_ws;
    _Float16* W1T    = (_Float16*)(ws);                        // 512 KB
    _Float16* WseT   = (_Float16*)(ws + (512 << 10));          // 512 KB
    _Float16* vsT    = (_Float16*)(ws + (1 << 20));            // 512 KB
    float*    s_part = (float*)(ws + (1536 << 10));            // 512 KB
    float*    msum   = (float*)(ws + (2 << 20));               // 1 MB
    _Float16* qH     = (_Float16*)(ws + (3 << 20));            // 512 KB
    _Float16* ksH    = (_Float16*)(ws + (3 << 20) + (512 << 10)); // 512 KB

    prep_kernel<<<dim3(16, 38), 256, 0, stream>>>(W1, W1T, Wse, WseT, vs, vsT,
                                                  qs1, qH, ks, ksH);
    gemm_h_kernel<<<dim3(BQ, 2), 512, 0, stream>>>(qH, ksH, sg, W1T, b1, W2, s_part, msum);
    final_kernel<<<dim3(16, 16), 256, 0, stream>>>(s_part, msum, sg, WseT, vsT, bse, b2, out);
}